// Round 3
// baseline (165.578 us; speedup 1.0000x reference)
//
#include <hip/hip_runtime.h>
#include <stdint.h>

// Problem constants: N=16384, M=1024, D=1024, fp32 in/out
#define NN 16384
#define MM 1024
#define DD 1024

typedef __attribute__((ext_vector_type(4)))  int   int4v;
typedef __attribute__((ext_vector_type(8)))  int   int8v;   // 32 fp8 (MX MFMA A/B frag)
typedef __attribute__((ext_vector_type(4)))  float f4;
typedef __attribute__((ext_vector_type(16))) float f16v;    // 32x32 MFMA C/D frag

// pack 4 fp32 -> 4 OCP e4m3 bytes in a dword (HW RNE)
__device__ __forceinline__ uint32_t pk4fp8(float a, float b, float c, float d) {
    uint32_t lo = __builtin_amdgcn_cvt_pk_fp8_f32(a, b, 0, false);
    return __builtin_amdgcn_cvt_pk_fp8_f32(c, d, lo, true);
}

// global -> LDS direct copy, 16B per lane (dest = wave-uniform base + lane*16)
#define GLD16(gsrc, ldst)                                                      \
    __builtin_amdgcn_global_load_lds(                                         \
        (const __attribute__((address_space(1))) void*)(gsrc),                \
        (__attribute__((address_space(3))) void*)(ldst), 16, 0, 0)

#define MFMA8(a_, b_, c_)                                                      \
    __builtin_amdgcn_mfma_scale_f32_32x32x64_f8f6f4(                           \
        (a_), (b_), (c_), 0, 0, 0, 0x7F7F7F7F, 0, 0x7F7F7F7F)

// ---- fused prologue (ONE dispatch): blocks [0,4352) do row squared-norms +
// fp32->fp8 convert of x and centers; blocks [4352,5376) transpose+convert
// norm [k][c] -> [c][k] fp8.
// All fp8 outputs are stored PRE-SWIZZLED in global memory (16B chunk index
// ^= row&7 within each 128B group, i.e. dword index ^= (row&7)<<2) so the
// GEMM can stage tiles with linear global_load_lds and read conflict-free. ----
#define ROW_BLOCKS ((NN + MM) / 4)   // 4352

__global__ __launch_bounds__(256)
void prologue_kernel(const float* __restrict__ x, const float* __restrict__ cen,
                     const float* __restrict__ norm,
                     float* __restrict__ xsq, float* __restrict__ csq,
                     uint32_t* __restrict__ x8, uint32_t* __restrict__ c8,
                     uint8_t* __restrict__ n8) {
    if (blockIdx.x < ROW_BLOCKS) {
        int row  = (blockIdx.x * 256 + threadIdx.x) >> 6;
        int lane = threadIdx.x & 63;
        const float* src; float* sq; uint32_t* ob;
        if (row < NN) { src = x + (size_t)row * DD;  sq = xsq + row;
                        ob = x8 + (size_t)row * (DD / 4); }
        else          { int r = row - NN;
                        src = cen + (size_t)r * DD;  sq = csq + r;
                        ob = c8 + (size_t)r * (DD / 4); }
        const int swz = (row & 7) << 2;     // NN%8==0 so (row-NN)&7 == row&7
        const f4* p = (const f4*)src;
        float s = 0.f;
        for (int i = lane; i < DD / 4; i += 64) {
            f4 v = p[i];
            s = fmaf(v.x, v.x, s); s = fmaf(v.y, v.y, s);
            s = fmaf(v.z, v.z, s); s = fmaf(v.w, v.w, s);
            ob[i ^ swz] = pk4fp8(v.x, v.y, v.z, v.w);   // pre-swizzled store
        }
#pragma unroll
        for (int off = 32; off > 0; off >>= 1) s += __shfl_down(s, off);
        if (lane == 0) *sq = s;
    } else {
        // norm transpose tile: 32x32
        __shared__ float t[32][33];
        int bid2 = blockIdx.x - ROW_BLOCKS;      // 0..1023
        int bx = bid2 & 31, by = bid2 >> 5;
        int tx = threadIdx.x & 31, ty = threadIdx.x >> 5;  // 32 x 8
#pragma unroll
        for (int i = 0; i < 32; i += 8)
            t[ty + i][tx] = norm[(size_t)(by * 32 + ty + i) * MM + bx * 32 + tx];
        __syncthreads();
        int c  = threadIdx.x >> 3;        // 0..31 (local col)
        int rg = (threadIdx.x & 7) * 4;   // 0,4,...,28 (local k group)
        uint32_t u = pk4fp8(t[rg + 0][c], t[rg + 1][c], t[rg + 2][c], t[rg + 3][c]);
        // pre-swizzled store: dword index within row d = by*8 + (tid&7)
        uint32_t* orow = (uint32_t*)&n8[(size_t)(bx * 32 + c) * MM];
        orow[(by * 8 + (threadIdx.x & 7)) ^ ((c & 7) << 2)] = u;
    }
}

// ---- MX-fp8 MFMA GEMM, ROUND 14: 256x256 tile, 8 waves (2M x 4N), wave tile
// 128x64 (4x2 accs of 32x32x64 -> 1.5 ds_reads/MFMA vs 2.0 at 64x64), BK=128,
// double-buffered LDS 2x64KB (1 block/CU), 8-phase schedule per K-tile:
// each phase = {ds_read frag(s) | stage issue} -> s_barrier -> lgkmcnt(0) ->
// setprio(1) -> 2 MFMAs -> setprio(0) -> s_barrier  (T3+T4+T5). Staging for
// tile t+1 is front-loaded into phases 0-3 of tile t, so the single vmcnt(0)
// at the iter boundary waits on ~4-phase-old loads (nearly free).
// Global fp8 operands PRE-SWIZZLED (chunk ^= row&7 per 128B) -> linear
// global_load_lds, XOR-swizzled ds_read, conflict-limited to 4-way.
// A: [row][k] fp8; Bt: [col][k] fp8. EXP_EPI: C(fp8, pre-swizzled)=
// exp(-g*(xsq+csq-2acc)); else C(fp32, linear)=acc.
constexpr int BM = 256, BN = 256, BK = 128;

__device__ __forceinline__ int8v rdfrag(const uint8_t* base, int row, int cb) {
    const uint8_t* p = base + row * BK;
    int4v lo = *(const int4v*)(p + ((cb ^ (row & 7)) * 16));
    int4v hi = *(const int4v*)(p + (((cb + 1) ^ (row & 7)) * 16));
    return __builtin_shufflevector(lo, hi, 0, 1, 2, 3, 4, 5, 6, 7);
}

template<bool EXP_EPI>
__global__ __launch_bounds__(512, 2)
void mfma_gemm_fp8(const uint8_t* __restrict__ A, const uint8_t* __restrict__ Bt,
                   void* __restrict__ Cv, const float* __restrict__ xsq,
                   const float* __restrict__ csq, const float* __restrict__ gamma_p)
{
    constexpr int K = 1024, NC = 1024, NIT = K / BK;   // 8 K-tiles
    __shared__ __align__(16) uint8_t sA[2][BM * BK];   // 2 x 32 KB
    __shared__ __align__(16) uint8_t sB[2][BN * BK];   // 2 x 32 KB

    const int tid  = threadIdx.x;
    const int lane = tid & 63;
    const int wave = tid >> 6;        // 0..7
    const int l31  = lane & 31;
    const int kh   = lane >> 5;
    const int wm   = (wave >> 2) * 128;   // 2 wave-rows
    const int wn   = (wave & 3) * 64;     // 4 wave-cols

    // bijective XCD swizzle: 256 blocks = 8 XCDs x 32 slots; consecutive
    // slots share a row-panel -> A-panel L2 locality within an XCD.
    const int bid  = blockIdx.x;           // 0..255
    const int xcd  = bid & 7;
    const int slot = bid >> 3;             // 0..31
    const int brow = (xcd * 8 + (slot >> 2)) * 256;
    const int bcol = (slot & 3) * 256;

    const float gam = EXP_EPI ? gamma_p[0] : 0.f;

    f16v acc[4][2];
#pragma unroll
    for (int mi = 0; mi < 4; ++mi)
#pragma unroll
        for (int ni = 0; ni < 2; ++ni)
#pragma unroll
            for (int r = 0; r < 16; ++r) acc[mi][ni][r] = 0.f;

    // staging: per issue, 512 threads x 16B = 8KB = 64 rows of 128B.
    // thread -> row = j*64 + wave*8 + (lane>>3), chunk = lane&7 (global is
    // pre-swizzled so a linear copy reproduces the swizzled LDS image).
    const int sr = wave * 8 + (lane >> 3);       // 0..63
    const int sc = lane & 7;
    const uint8_t* ga = A  + (size_t)(brow + sr) * K + sc * 16;
    const uint8_t* gb = Bt + (size_t)(bcol + sr) * K + sc * 16;

    // prologue: stage tile 0 (8 issues), full drain once
    {
        uint8_t* dA = &sA[0][wave * 1024];
        uint8_t* dB = &sB[0][wave * 1024];
#pragma unroll
        for (int j = 0; j < 4; ++j) {
            GLD16(ga + (size_t)j * 64 * K, dA + j * 8192);
            GLD16(gb + (size_t)j * 64 * K, dB + j * 8192);
        }
    }
    asm volatile("s_waitcnt vmcnt(0)" ::: "memory");
    __builtin_amdgcn_s_barrier();

#pragma unroll
    for (int it = 0; it < NIT; ++it) {
        const int cur = it & 1;
        const uint8_t* tA = &sA[cur][0];
        const uint8_t* tB = &sB[cur][0];
        uint8_t* dA = &sA[cur ^ 1][wave * 1024];
        uint8_t* dB = &sB[cur ^ 1][wave * 1024];
        const size_t koff = (size_t)(it + 1) * BK;
        const bool st = (it + 1 < NIT);

        int8v b0, b1, am;

        // PHASE(mi, s): optional stage pair; reads; bar; lgkm0; 2 MFMA; bar
#define PHASE(mi_, s_, STG)                                                    \
        do {                                                                   \
            STG;                                                               \
            if ((mi_) == 0) {                                                  \
                b0 = rdfrag(tB, wn + l31,      (s_) * 4 + kh * 2);             \
                b1 = rdfrag(tB, wn + 32 + l31, (s_) * 4 + kh * 2);             \
            }                                                                  \
            am = rdfrag(tA, wm + (mi_) * 32 + l31, (s_) * 4 + kh * 2);         \
            __builtin_amdgcn_s_barrier();                                      \
            asm volatile("s_waitcnt lgkmcnt(0)" ::: "memory");                 \
            __builtin_amdgcn_s_setprio(1);                                     \
            acc[mi_][0] = MFMA8(am, b0, acc[mi_][0]);                          \
            acc[mi_][1] = MFMA8(am, b1, acc[mi_][1]);                          \
            __builtin_amdgcn_s_setprio(0);                                     \
            __builtin_amdgcn_s_barrier();                                      \
        } while (0)

        // s = 0 half: staging for tile it+1 front-loaded here (2 issues/phase)
        PHASE(0, 0, if (st) { GLD16(ga + koff,                    dA);
                              GLD16(ga + koff + (size_t) 64 * K,  dA +  8192); });
        PHASE(1, 0, if (st) { GLD16(ga + koff + (size_t)128 * K,  dA + 16384);
                              GLD16(ga + koff + (size_t)192 * K,  dA + 24576); });
        PHASE(2, 0, if (st) { GLD16(gb + koff,                    dB);
                              GLD16(gb + koff + (size_t) 64 * K,  dB +  8192); });
        PHASE(3, 0, if (st) { GLD16(gb + koff + (size_t)128 * K,  dB + 16384);
                              GLD16(gb + koff + (size_t)192 * K,  dB + 24576); });
        // s = 1 half: no staging; loads above age ~4 phases before the wait
        PHASE(0, 1, );
        PHASE(1, 1, );
        PHASE(2, 1, );
        PHASE(3, 1, );
#undef PHASE

        // iter boundary: own loads drained by every wave, then barrier ->
        // tile it+1 fully resident before any wave reads it.
        asm volatile("s_waitcnt vmcnt(0)" ::: "memory");
        __builtin_amdgcn_s_barrier();
    }

    // C/D layout (32x32, m74/m101): col = lane&31, row = (reg&3)+8*(reg>>2)+4*kh
    if constexpr (EXP_EPI) {
        uint8_t* C = (uint8_t*)Cv;
        float cs[2];
        cs[0] = csq[bcol + wn + l31];
        cs[1] = csq[bcol + wn + 32 + l31];
#pragma unroll
        for (int mi = 0; mi < 4; ++mi)
#pragma unroll
            for (int r = 0; r < 16; ++r) {
                int rl  = (r & 3) + 8 * (r >> 2) + 4 * kh;
                int row = brow + wm + mi * 32 + rl;
                float xs = xsq[row];
                int rsw = (row & 7) << 4;   // pre-swizzle for stage-2 staging
#pragma unroll
                for (int ni = 0; ni < 2; ++ni) {
                    int col = bcol + wn + ni * 32 + l31;
                    float sq = xs + cs[ni] - 2.0f * acc[mi][ni][r];
                    float d = __expf(-gam * sq);   // underflows to 0 (sq ~>1500)
                    C[(size_t)row * NC + (col ^ rsw)] =
                        (uint8_t)(__builtin_amdgcn_cvt_pk_fp8_f32(d, d, 0, false) & 0xFF);
                }
            }
    } else {
        float* C = (float*)Cv;
#pragma unroll
        for (int mi = 0; mi < 4; ++mi)
#pragma unroll
            for (int r = 0; r < 16; ++r) {
                int rl  = (r & 3) + 8 * (r >> 2) + 4 * kh;
                int row = brow + wm + mi * 32 + rl;
#pragma unroll
                for (int ni = 0; ni < 2; ++ni)
                    C[(size_t)row * NC + bcol + wn + ni * 32 + l31] = acc[mi][ni][r];
            }
    }
}

extern "C" void kernel_launch(void* const* d_in, const int* in_sizes, int n_in,
                              void* d_out, int out_size, void* d_ws, size_t ws_size,
                              hipStream_t stream) {
    const float* inputs  = (const float*)d_in[0];   // [N, D]
    const float* centers = (const float*)d_in[1];   // [M, D]
    const float* gamma   = (const float*)d_in[2];   // [1]
    const float* norm    = (const float*)d_in[3];   // [M, M]
    float* out = (float*)d_out;                     // [N, M]

    // ws layout: xsq 64K | csq 4K | c8 1M | n8 1M | dens8 16M  (~18.1 MiB)
    char* w = (char*)d_ws;
    float*   xsq   = (float*)w;
    float*   csq   = (float*)(w + 65536);
    uint8_t* c8    = (uint8_t*)(w + 69632);
    uint8_t* n8    = (uint8_t*)(w + 69632 + (1u << 20));
    uint8_t* dens8 = (uint8_t*)(w + 69632 + (2u << 20));
    // x8 (16 MB) parked in d_out: dead before stage 2 writes d_out.
    uint32_t* x8   = (uint32_t*)d_out;

    // single fused prologue dispatch (rowsq+cvt for x & centers, norm transpose)
    prologue_kernel<<<ROW_BLOCKS + 1024, 256, 0, stream>>>(
        inputs, centers, norm, xsq, csq, x8, (uint32_t*)c8, n8);

    // stage 1: dens = exp(-g * (xsq + csq - 2 * x @ centers^T)), fp8 out
    mfma_gemm_fp8<true><<<256, 512, 0, stream>>>(
        (const uint8_t*)x8, c8, dens8, xsq, csq, gamma);
    // stage 2: out = dens @ norm (via norm^T), fp32 out
    mfma_gemm_fp8<false><<<256, 512, 0, stream>>>(
        dens8, n8, out, nullptr, nullptr, nullptr);
}